// Round 16
// baseline (213.438 us; speedup 1.0000x reference)
//
#include <hip/hip_runtime.h>
#include <math.h>

#define BB 4
#define CC 512
#define TT 4096
#define NN2 32
#define HH 2048

typedef __bf16 bf8v __attribute__((ext_vector_type(8)));
typedef __bf16 bf4v __attribute__((ext_vector_type(4)));
typedef float  f4v  __attribute__((ext_vector_type(4)));
typedef float  f16v __attribute__((ext_vector_type(16)));
typedef unsigned short u16x8 __attribute__((ext_vector_type(8)));

__device__ __forceinline__ void gload16(const void* g, void* l){
  __builtin_amdgcn_global_load_lds(
      (const __attribute__((address_space(1))) unsigned int*)g,
      (__attribute__((address_space(3))) unsigned int*)l, 16, 0, 0);
}
__device__ __forceinline__ float fast_gelu(float v){
  float x2 = v*v;
  float x  = 0.7978845608f*v*fmaf(0.044715f, x2, 1.0f);
  float t  = __expf(2.0f*x);
  return v - v*__builtin_amdgcn_rcpf(1.0f + t);
}
__device__ __forceinline__ float fast_sigmoid(float g){
  return __builtin_amdgcn_rcpf(1.0f + __expf(-g));
}
__device__ __forceinline__ unsigned short bfbits(float v){
  __bf16 h = (__bf16)v;
  return __builtin_bit_cast(unsigned short, h);
}

// ---------------- ChannelwiseLayerNorm, ONE-PASS (x cached in registers) ----------------
__global__ __launch_bounds__(256) void ln_kernel(
    const float* __restrict__ x, const float* __restrict__ gamma,
    const float* __restrict__ beta, __bf16* __restrict__ u)
{
  int tile = blockIdx.x & 127;
  int b    = blockIdx.x >> 7;
  int tsl = threadIdx.x & 7;
  int cg  = threadIdx.x >> 3;
  const float4* xp = (const float4*)(x + (size_t)b*CC*TT + tile*32) + tsl;
  float4 cv[16];
  float4 s = {0,0,0,0}, s2 = {0,0,0,0};
  #pragma unroll
  for (int j = 0; j < 16; ++j){
    float4 v = xp[(size_t)(cg*16 + j)*(TT/4)];
    cv[j] = v;
    s.x += v.x; s.y += v.y; s.z += v.z; s.w += v.w;
    s2.x = fmaf(v.x,v.x,s2.x); s2.y = fmaf(v.y,v.y,s2.y);
    s2.z = fmaf(v.z,v.z,s2.z); s2.w = fmaf(v.w,v.w,s2.w);
  }
  __shared__ float4 ls[32][8], ls2[32][8], mean_s[8], inv_s[8];
  ls[cg][tsl] = s; ls2[cg][tsl] = s2;
  __syncthreads();
  if (threadIdx.x < 8){
    float4 ss = {0,0,0,0}, ss2 = {0,0,0,0};
    #pragma unroll
    for (int g2 = 0; g2 < 32; ++g2){
      float4 a = ls[g2][threadIdx.x], b2 = ls2[g2][threadIdx.x];
      ss.x+=a.x; ss.y+=a.y; ss.z+=a.z; ss.w+=a.w;
      ss2.x+=b2.x; ss2.y+=b2.y; ss2.z+=b2.z; ss2.w+=b2.w;
    }
    float4 mn, iv;
    mn.x = ss.x*(1.f/CC); mn.y = ss.y*(1.f/CC); mn.z = ss.z*(1.f/CC); mn.w = ss.w*(1.f/CC);
    iv.x = rsqrtf(ss2.x*(1.f/CC) - mn.x*mn.x + 1e-5f);
    iv.y = rsqrtf(ss2.y*(1.f/CC) - mn.y*mn.y + 1e-5f);
    iv.z = rsqrtf(ss2.z*(1.f/CC) - mn.z*mn.z + 1e-5f);
    iv.w = rsqrtf(ss2.w*(1.f/CC) - mn.w*mn.w + 1e-5f);
    mean_s[threadIdx.x] = mn; inv_s[threadIdx.x] = iv;
  }
  __syncthreads();
  float4 mn = mean_s[tsl], iv = inv_s[tsl];
  __bf16* up = u + (size_t)b*CC*TT + tile*32 + tsl*4;
  #pragma unroll
  for (int j = 0; j < 16; ++j){
    int c = cg*16 + j;
    float4 v = cv[j];
    float gi = gamma[c], be = beta[c];
    bf4v o;
    o[0] = (__bf16)fmaf(gi*iv.x, v.x - mn.x, be);
    o[1] = (__bf16)fmaf(gi*iv.y, v.y - mn.y, be);
    o[2] = (__bf16)fmaf(gi*iv.z, v.z - mn.z, be);
    o[3] = (__bf16)fmaf(gi*iv.w, v.w - mn.w, be);
    *(bf4v*)&up[(size_t)c*TT] = o;
  }
}

// ---------------- build per-channel S4D basis matrices (bf16) ----------------
__global__ __launch_bounds__(256) void build_mats(
    const float* __restrict__ log_dt, const float* __restrict__ C_re,
    const float* __restrict__ C_im, const float* __restrict__ log_A_real,
    const float* __restrict__ A_imag, const float* __restrict__ Dp,
    __bf16* __restrict__ Tt, __bf16* __restrict__ V, __bf16* __restrict__ B2)
{
  __shared__ float cpart[4][64][33];
  __shared__ float kk[4][65];
  const int wv = threadIdx.x >> 6, lane = threadIdx.x & 63;
  const int c = blockIdx.x*4 + wv;
  const int m = lane & 31;
  float dt = expf(log_dt[c]);
  float Ar = -expf(log_A_real[c*NN2+m]);
  float Ai = A_imag[c*NN2+m];
  float er = expf(Ar*dt);
  float sw_, cw_; sincosf(Ai*dt, &sw_, &cw_);
  float wre = er*cw_, wim = er*sw_;
  float nr = wre-1.f, ni = wim;
  float inv = 1.f/(Ar*Ar + Ai*Ai);
  float qr = (nr*Ar + ni*Ai)*inv;
  float qi = (ni*Ar - nr*Ai)*inv;
  float Cr = C_re[c*NN2+m], Ci = C_im[c*NN2+m];
  float okr =  2.f*(Cr*qr - Ci*qi);
  float oki = -2.f*(Cr*qi + Ci*qr);
  __bf16* Ttc = Tt + (size_t)c*4096;
  __bf16* Vc  = V  + (size_t)c*4096;
  __bf16* B2c = B2 + (size_t)c*4096;
  if (lane < 32){
    float pre = 1.f, pim = 0.f;
    for (int l = 0; l <= 64; ++l){
      if (l <= 63){
        Vc[(2*m)*64   + (63-l)] = (__bf16)pre;
        Vc[(2*m+1)*64 + (63-l)] = (__bf16)pim;
      }
      float cR = fmaf(okr, pre,  oki*pim);
      float cQ = fmaf(oki, pre, -okr*pim);
      if (l <= 63) cpart[wv][l][m] = cR;
      if (l >= 1){
        B2c[(l-1)*64 + 2*m]   = (__bf16)cR;
        B2c[(l-1)*64 + 2*m+1] = (__bf16)cQ;
      }
      float npre = wre*pre - wim*pim;
      float npim = wre*pim + wim*pre;
      pre = npre; pim = npim;
    }
  }
  __syncthreads();
  float s = 0.f;
  #pragma unroll
  for (int mm = 0; mm < 32; ++mm) s += cpart[wv][lane][mm];
  if (lane == 0) s += Dp[c];
  kk[wv][lane] = s;
  __syncthreads();
  const int n = lane;
  #pragma unroll
  for (int kb = 0; kb < 8; ++kb){
    u16x8 v;
    #pragma unroll
    for (int e = 0; e < 8; ++e){
      int k = kb*8 + e;
      v[e] = bfbits((n >= k) ? kk[wv][n-k] : 0.f);
    }
    *(u16x8*)&Ttc[n*64 + kb*8] = v;
  }
}

// ---------------- fused S4D via MFMA: G=U@V -> scan -> Y=U@Tt+S0@B2 -> gelu ----------------
__global__ __launch_bounds__(128) void s4dm_kernel(
    const __bf16* __restrict__ u, const float* __restrict__ log_dt,
    const float* __restrict__ log_A_real, const float* __restrict__ A_imag,
    const __bf16* __restrict__ Tt, const __bf16* __restrict__ V,
    const __bf16* __restrict__ B2, __bf16* __restrict__ gout)
{
  __shared__ __align__(16) float gbuf[2][64][66];
  __shared__ __align__(16) unsigned short s0buf[2][64][72];
  const int wv = threadIdx.x >> 6, l = threadIdx.x & 63;
  const int lr = l & 15, q = l >> 4;
  const int seq = blockIdx.x*2 + wv;
  const int c = seq & (CC-1);
  const __bf16* Up  = u  + (size_t)seq*TT;
  const __bf16* Ttc = Tt + (size_t)c*4096;
  const __bf16* Vc  = V  + (size_t)c*4096;
  const __bf16* B2c = B2 + (size_t)c*4096;

  f4v acc[4][4];
  #pragma unroll
  for (int a=0;a<4;++a)
    #pragma unroll
    for (int b=0;b<4;++b)
      #pragma unroll
      for (int r=0;r<4;++r) acc[a][b][r] = 0.f;

  #pragma unroll
  for (int kw = 0; kw < 2; ++kw){
    bf8v af[4], bv[4];
    #pragma unroll
    for (int mt=0;mt<4;++mt)
      af[mt] = *(const bf8v*)(Up + (mt*16+lr)*64 + kw*32 + q*8);
    #pragma unroll
    for (int nt=0;nt<4;++nt)
      bv[nt] = *(const bf8v*)(Vc + (nt*16+lr)*64 + kw*32 + q*8);
    #pragma unroll
    for (int mt=0;mt<4;++mt)
      #pragma unroll
      for (int nt=0;nt<4;++nt)
        acc[mt][nt] = __builtin_amdgcn_mfma_f32_16x16x32_bf16(af[mt], bv[nt], acc[mt][nt], 0,0,0);
  }
  #pragma unroll
  for (int mt=0;mt<4;++mt)
    #pragma unroll
    for (int nt=0;nt<4;++nt)
      #pragma unroll
      for (int r=0;r<4;++r)
        gbuf[wv][mt*16 + q*4 + r][nt*16 + lr] = acc[mt][nt][r];
  __syncthreads();

  if (l < 32){
    const int m = l;
    float dt = expf(log_dt[c]);
    float Ar = -expf(log_A_real[c*NN2+m]);
    float Ai = A_imag[c*NN2+m];
    float er = expf(Ar*dt);
    float sw_, cw_; sincosf(Ai*dt, &sw_, &cw_);
    float wr_ = er*cw_, wi_ = er*sw_;
    #pragma unroll
    for (int sq2=0;sq2<6;++sq2){
      float a=wr_, b=wi_;
      wr_ = a*a - b*b; wi_ = 2.f*a*b;
    }
    float S0r=0.f, S0i=0.f;
    for (int j=0;j<64;++j){
      float gr = gbuf[wv][j][2*m], gi = gbuf[wv][j][2*m+1];
      s0buf[wv][j][2*m]   = bfbits(S0r);
      s0buf[wv][j][2*m+1] = bfbits(S0i);
      float nRe = fmaf(wr_, S0r, fmaf(-wi_, S0i, gr));
      float nIm = fmaf(wr_, S0i, fmaf( wi_, S0r, gi));
      S0r = nRe; S0i = nIm;
    }
  }
  __syncthreads();

  #pragma unroll
  for (int a=0;a<4;++a)
    #pragma unroll
    for (int b=0;b<4;++b)
      #pragma unroll
      for (int r=0;r<4;++r) acc[a][b][r] = 0.f;
  #pragma unroll
  for (int kw = 0; kw < 2; ++kw){
    bf8v af[4], bv[4];
    #pragma unroll
    for (int mt=0;mt<4;++mt)
      af[mt] = *(const bf8v*)(Up + (mt*16+lr)*64 + kw*32 + q*8);
    #pragma unroll
    for (int nt=0;nt<4;++nt)
      bv[nt] = *(const bf8v*)(Ttc + (nt*16+lr)*64 + kw*32 + q*8);
    #pragma unroll
    for (int mt=0;mt<4;++mt)
      #pragma unroll
      for (int nt=0;nt<4;++nt)
        acc[mt][nt] = __builtin_amdgcn_mfma_f32_16x16x32_bf16(af[mt], bv[nt], acc[mt][nt], 0,0,0);
  }
  #pragma unroll
  for (int kw = 0; kw < 2; ++kw){
    bf8v af[4], bv[4];
    #pragma unroll
    for (int mt=0;mt<4;++mt)
      af[mt] = *(const bf8v*)&s0buf[wv][mt*16+lr][kw*32 + q*8];
    #pragma unroll
    for (int nt=0;nt<4;++nt)
      bv[nt] = *(const bf8v*)(B2c + (nt*16+lr)*64 + kw*32 + q*8);
    #pragma unroll
    for (int mt=0;mt<4;++mt)
      #pragma unroll
      for (int nt=0;nt<4;++nt)
        acc[mt][nt] = __builtin_amdgcn_mfma_f32_16x16x32_bf16(af[mt], bv[nt], acc[mt][nt], 0,0,0);
  }
  __syncthreads();

  unsigned short (*ybuf)[72] = (unsigned short(*)[72])&gbuf[wv][0][0];
  #pragma unroll
  for (int mt=0;mt<4;++mt)
    #pragma unroll
    for (int nt=0;nt<4;++nt)
      #pragma unroll
      for (int r=0;r<4;++r)
        ybuf[mt*16 + q*4 + r][nt*16 + lr] = bfbits(fast_gelu(acc[mt][nt][r]));
  __syncthreads();
  u16x8* dst = (u16x8*)(gout + (size_t)seq*TT);
  for (int i = l; i < 512; i += 64){
    int row = i >> 3, cq = i & 7;
    dst[i] = *(const u16x8*)&ybuf[row][cq*8];
  }
}

// ---------------- transpose [B][C][T] bf16 -> [B][T][C] bf16 ----------------
__global__ __launch_bounds__(256) void tr_kernel(const __bf16* __restrict__ gin,
                                                 __bf16* __restrict__ gout)
{
  __shared__ __align__(16) unsigned short ts[64][72];
  int bt = blockIdx.x;
  int bc = blockIdx.y;
  int b  = blockIdx.z;
  int tid = threadIdx.x;
  const __bf16* gp = gin + ((size_t)b*CC + bc*64)*TT + (size_t)bt*64;
  for (int i = tid; i < 512; i += 256){
    int c = i >> 3, tq = i & 7;
    u16x8 v = *(const u16x8*)(gp + (size_t)c*TT + tq*8);
    #pragma unroll
    for (int s = 0; s < 8; ++s) ts[tq*8+s][c] = v[s];
  }
  __syncthreads();
  __bf16* op = gout + ((size_t)b*TT + bt*64)*CC + bc*64;
  for (int i = tid; i < 512; i += 256){
    int t = i >> 3, cq = i & 7;
    u16x8 v = *(const u16x8*)&ts[t][cq*8];
    *(u16x8*)(op + (size_t)t*CC + cq*8) = v;
  }
}

// ---------------- fp32 -> bf16 weight convert ----------------
__global__ __launch_bounds__(256) void cvt_kernel(const float4* __restrict__ in,
                                                  bf4v* __restrict__ out, int n4)
{
  int i = blockIdx.x*256 + threadIdx.x;
  if (i < n4){
    float4 v = in[i];
    bf4v o; o[0]=(__bf16)v.x; o[1]=(__bf16)v.y; o[2]=(__bf16)v.z; o[3]=(__bf16)v.w;
    out[i] = o;
  }
}

// ---------------- bf16 MFMA GEMM — round-15 structure, 32x32x16 MFMA ----------------
// Serial single-buffer, BK=64, 128x128 tile, 256 thr (2x2 waves, 64x64 wave tile,
// 2x2 frags of 32x32). Same LDS layout/swizzle/staging as before; half the MFMA
// instruction count per K-step. C/D map: col=lane&31, row=(reg&3)+8*(reg>>2)+4*(lane>>5).
// MODE 0: GLU   — A=Wo[1024][512] dual, B=g_tm, out glu bf16 [tok][C]
// MODE 1: PReLU — A=W1[2048][512],      B=glu,  out h bf16 [tok][H]
// MODE 2: resid — A=h[16384][2048] (TOKENS as M), B=W2[512][2048], out fp32 +resid
template<int MODE>
__global__ __launch_bounds__(256) void mm_kernel(
    const __bf16* __restrict__ Aw, const __bf16* __restrict__ Bt,
    const float* __restrict__ bias, const float* __restrict__ aux,
    void* __restrict__ outp)
{
  constexpr int K  = (MODE==2) ? 2048 : 512;
  constexpr int NT = K/64;

  __shared__ __align__(16) __bf16 As[128*64];
  __shared__ __align__(16) __bf16 Bs[128*64];
  __shared__ __align__(16) __bf16 As2[(MODE==0)?128*64:8];

  const int bid = blockIdx.x;
  const int X = bid & 7, L = bid >> 3;
  int m0, n0;
  if constexpr (MODE==0){       // grid 512: 4 weight-tiles x 128 token-tiles
    m0 = (L & 3) * 128;  n0 = (X*16 + (L >> 2)) * 128;
  } else if constexpr (MODE==1){// grid 2048: 16 weight-tiles x 128 token-tiles
    m0 = (L & 15) * 128; n0 = (X*16 + (L >> 4)) * 128;
  } else {                      // grid 512: 128 token-tiles (M) x 4 ch-tiles (N)
    n0 = (L & 3) * 128;  m0 = (X*16 + (L >> 2)) * 128;
  }

  const int tid = threadIdx.x;
  const int l = tid & 63;
  const int l31 = l & 31, kp = l >> 5;   // frag row, k-part for 32x32x16
  const int w = tid >> 6;
  const int wr = w >> 1, wc = w & 1;
  const int swk = l & 7;

  f16v acc[2][2];
  f16v acc2[(MODE==0)?2:1][(MODE==0)?2:1];
  #pragma unroll
  for (int a=0;a<2;++a)
    #pragma unroll
    for (int b=0;b<2;++b)
      #pragma unroll
      for (int r=0;r<16;++r){
        acc[a][b][r] = 0.f;
        if constexpr (MODE==0) acc2[a][b][r] = 0.f;
      }

  const char* pA  = (const char*)Aw;
  const char* pA2 = (const char*)(Aw + (size_t)CC*K);
  const char* pB  = (const char*)Bt;

  int offA[4], offB[4];
  #pragma unroll
  for (int i = 0; i < 4; ++i){
    int cch = i*256 + tid;
    int row = cch >> 3;
    int pos = cch & 7;
    int qq  = pos ^ (row & 7);
    offA[i] = ((m0 + row)*K + qq*8)*2;
    offB[i] = ((n0 + row)*K + qq*8)*2;
  }

  const int rowA0 = (wr*64 +      l31)*128;
  const int rowA1 = (wr*64 + 32 + l31)*128;
  const int rowB0 = (wc*64 +      l31)*128;
  const int rowB1 = (wc*64 + 32 + l31)*128;

  #pragma unroll 1
  for (int kt = 0; kt < NT; ++kt){
    // ---- stage one BK=64 slab ----
    #pragma unroll
    for (int i = 0; i < 4; ++i){
      int cch = i*256 + tid;
      gload16(pA + (size_t)offA[i] + kt*128, (char*)As + cch*16);
      gload16(pB + (size_t)offB[i] + kt*128, (char*)Bs + cch*16);
      if constexpr (MODE==0)
        gload16(pA2 + (size_t)offA[i] + kt*128, (char*)As2 + cch*16);
    }
    __syncthreads();

    // ---- compute: 4 k-steps of 16 (32x32x16 MFMA) ----
    #pragma unroll
    for (int ks = 0; ks < 4; ++ks){
      const int coff = ((ks*2 + kp) ^ swk) * 16;
      bf8v a0 = *(const bf8v*)((const char*)As + rowA0 + coff);
      bf8v a1 = *(const bf8v*)((const char*)As + rowA1 + coff);
      bf8v b0 = *(const bf8v*)((const char*)Bs + rowB0 + coff);
      bf8v b1 = *(const bf8v*)((const char*)Bs + rowB1 + coff);
      if constexpr (MODE==0){
        bf8v g0 = *(const bf8v*)((const char*)As2 + rowA0 + coff);
        bf8v g1 = *(const bf8v*)((const char*)As2 + rowA1 + coff);
        acc [0][0] = __builtin_amdgcn_mfma_f32_32x32x16_bf16(a0, b0, acc [0][0], 0,0,0);
        acc [0][1] = __builtin_amdgcn_mfma_f32_32x32x16_bf16(a0, b1, acc [0][1], 0,0,0);
        acc [1][0] = __builtin_amdgcn_mfma_f32_32x32x16_bf16(a1, b0, acc [1][0], 0,0,0);
        acc [1][1] = __builtin_amdgcn_mfma_f32_32x32x16_bf16(a1, b1, acc [1][1], 0,0,0);
        acc2[0][0] = __builtin_amdgcn_mfma_f32_32x32x16_bf16(g0, b0, acc2[0][0], 0,0,0);
        acc2[0][1] = __builtin_amdgcn_mfma_f32_32x32x16_bf16(g0, b1, acc2[0][1], 0,0,0);
        acc2[1][0] = __builtin_amdgcn_mfma_f32_32x32x16_bf16(g1, b0, acc2[1][0], 0,0,0);
        acc2[1][1] = __builtin_amdgcn_mfma_f32_32x32x16_bf16(g1, b1, acc2[1][1], 0,0,0);
      } else {
        acc[0][0] = __builtin_amdgcn_mfma_f32_32x32x16_bf16(a0, b0, acc[0][0], 0,0,0);
        acc[0][1] = __builtin_amdgcn_mfma_f32_32x32x16_bf16(a0, b1, acc[0][1], 0,0,0);
        acc[1][0] = __builtin_amdgcn_mfma_f32_32x32x16_bf16(a1, b0, acc[1][0], 0,0,0);
        acc[1][1] = __builtin_amdgcn_mfma_f32_32x32x16_bf16(a1, b1, acc[1][1], 0,0,0);
      }
    }
    __syncthreads();
  }

  // ---- epilogues (C/D: col=lane&31, row=(reg&3)+8*(reg>>2)+4*kp) ----
  if constexpr (MODE==0 || MODE==1){
    const int COUT = (MODE==0) ? CC : HH;
    __bf16* O = (__bf16*)outp;
    #pragma unroll
    for (int mi=0;mi<2;++mi){
      #pragma unroll
      for (int q2=0;q2<4;++q2){
        int m = m0 + wr*64 + mi*32 + q2*8 + kp*4;
        float4 bi = *(const float4*)&bias[m];
        float bia[4] = {bi.x, bi.y, bi.z, bi.w};
        float gta[4], paa[4];
        if constexpr (MODE==0){
          float4 bg = *(const float4*)&bias[CC + m];
          gta[0]=bg.x; gta[1]=bg.y; gta[2]=bg.z; gta[3]=bg.w;
        } else {
          float4 pa = *(const float4*)&aux[m];
          paa[0]=pa.x; paa[1]=pa.y; paa[2]=pa.z; paa[3]=pa.w;
        }
        #pragma unroll
        for (int ni=0;ni<2;++ni){
          int tok = n0 + wc*64 + ni*32 + l31;
          bf4v o;
          #pragma unroll
          for (int r=0;r<4;++r){
            float v = acc[mi][ni][q2*4 + r] + bia[r];
            if constexpr (MODE==0){
              float gate = acc2[mi][ni][q2*4 + r] + gta[r];
              v = v * fast_sigmoid(gate);
            } else {
              v = (v >= 0.f) ? v : paa[r]*v;
            }
            o[r] = (__bf16)v;
          }
          *(bf4v*)&O[(size_t)tok*COUT + m] = o;
        }
      }
    }
  } else {
    float* O = (float*)outp;
    #pragma unroll
    for (int mi=0;mi<2;++mi){
      #pragma unroll
      for (int q2=0;q2<4;++q2){
        int tok = m0 + wr*64 + mi*32 + q2*8 + kp*4;   // 4 consecutive tokens
        int b = tok >> 12, t = tok & 4095;
        #pragma unroll
        for (int ni=0;ni<2;++ni){
          int ch = n0 + wc*64 + ni*32 + l31;
          float bb = bias[ch];
          size_t rb = ((size_t)(b*CC + ch))*TT + t;
          float4 xr = *(const float4*)&aux[rb];
          float4 o;
          o.x = acc[mi][ni][q2*4 + 0] + bb + xr.x;
          o.y = acc[mi][ni][q2*4 + 1] + bb + xr.y;
          o.z = acc[mi][ni][q2*4 + 2] + bb + xr.z;
          o.w = acc[mi][ni][q2*4 + 3] + bb + xr.w;
          *(float4*)&O[rb] = o;
        }
      }
    }
  }
}

// ---------------- host launch ----------------
extern "C" void kernel_launch(void* const* d_in, const int* in_sizes, int n_in,
                              void* d_out, int out_size, void* d_ws, size_t ws_size,
                              hipStream_t stream)
{
  const float* x          = (const float*)d_in[0];
  const float* gamma      = (const float*)d_in[1];
  const float* beta       = (const float*)d_in[2];
  const float* log_dt     = (const float*)d_in[3];
  const float* C_re       = (const float*)d_in[4];
  const float* C_im       = (const float*)d_in[5];
  const float* log_A_real = (const float*)d_in[6];
  const float* A_imag     = (const float*)d_in[7];
  const float* Dp         = (const float*)d_in[8];
  const float* Wo         = (const float*)d_in[9];
  const float* bo         = (const float*)d_in[10];
  const float* W1         = (const float*)d_in[11];
  const float* b1         = (const float*)d_in[12];
  const float* prelu_a    = (const float*)d_in[13];
  const float* W2         = (const float*)d_in[14];
  const float* b2         = (const float*)d_in[15];
  float* out = (float*)d_out;

  char* base = (char*)d_ws;
  const size_t SEGB = (size_t)BB*CC*TT*2;        // 16.78 MB bf16 plane
  __bf16* u_bf  = (__bf16*)(base);               // [B][C][T]
  __bf16* glu   = (__bf16*)(base);               // aliases u_bf (dead after s4dm)
  __bf16* g_cm  = (__bf16*)(base + SEGB);        // [B][C][T]
  __bf16* g_tm  = (__bf16*)(base + 2*SEGB);      // [B*T][C]
  __bf16* h     = (__bf16*)(base + SEGB);        // [16384][H] over dead g_cm/g_tm
  __bf16* Tt_all = (__bf16*)(base + 2*SEGB);     // basis alias g_tm (dead before tr)
  __bf16* V_all  = Tt_all + (size_t)CC*4096;
  __bf16* B2_all = V_all  + (size_t)CC*4096;
  __bf16* Wo_bf = (__bf16*)(base + 5*SEGB);      // weights: 5 MB
  __bf16* W1_bf = Wo_bf + (size_t)2*CC*CC;
  __bf16* W2_bf = W1_bf + (size_t)HH*CC;

  cvt_kernel<<<dim3((2*CC*CC/4 + 255)/256), 256, 0, stream>>>((const float4*)Wo, (bf4v*)Wo_bf, 2*CC*CC/4);
  cvt_kernel<<<dim3((HH*CC/4 + 255)/256), 256, 0, stream>>>((const float4*)W1, (bf4v*)W1_bf, HH*CC/4);
  cvt_kernel<<<dim3((CC*HH/4 + 255)/256), 256, 0, stream>>>((const float4*)W2, (bf4v*)W2_bf, CC*HH/4);

  build_mats<<<dim3(CC/4), 256, 0, stream>>>(log_dt, C_re, C_im, log_A_real,
                                             A_imag, Dp, Tt_all, V_all, B2_all);
  ln_kernel<<<dim3(BB*(TT/32)), 256, 0, stream>>>(x, gamma, beta, u_bf);
  s4dm_kernel<<<dim3((BB*CC)/2), 128, 0, stream>>>(u_bf, log_dt, log_A_real, A_imag,
                                                   Tt_all, V_all, B2_all, g_cm);
  tr_kernel<<<dim3(TT/64, CC/64, BB), 256, 0, stream>>>(g_cm, g_tm);

  mm_kernel<0><<<dim3(4*128),  256, 0, stream>>>(Wo_bf, g_tm, bo, nullptr, (void*)glu);
  mm_kernel<1><<<dim3(16*128), 256, 0, stream>>>(W1_bf, glu, b1, prelu_a, (void*)h);
  mm_kernel<2><<<dim3(4*128),  256, 0, stream>>>(h, W2_bf, b2, x, (void*)out);
}

// Round 17
// 203.078 us; speedup vs baseline: 1.0510x; 1.0510x over previous
//
#include <hip/hip_runtime.h>
#include <math.h>

#define BB 4
#define CC 512
#define TT 4096
#define NN2 32
#define HH 2048

typedef __bf16 bf8v __attribute__((ext_vector_type(8)));
typedef __bf16 bf4v __attribute__((ext_vector_type(4)));
typedef float  f4v  __attribute__((ext_vector_type(4)));
typedef unsigned short u16x8 __attribute__((ext_vector_type(8)));

__device__ __forceinline__ void gload16(const void* g, void* l){
  __builtin_amdgcn_global_load_lds(
      (const __attribute__((address_space(1))) unsigned int*)g,
      (__attribute__((address_space(3))) unsigned int*)l, 16, 0, 0);
}
__device__ __forceinline__ float fast_gelu(float v){
  float x2 = v*v;
  float x  = 0.7978845608f*v*fmaf(0.044715f, x2, 1.0f);
  float t  = __expf(2.0f*x);
  return v - v*__builtin_amdgcn_rcpf(1.0f + t);
}
__device__ __forceinline__ float fast_sigmoid(float g){
  return __builtin_amdgcn_rcpf(1.0f + __expf(-g));
}
__device__ __forceinline__ unsigned short bfbits(float v){
  __bf16 h = (__bf16)v;
  return __builtin_bit_cast(unsigned short, h);
}

// ---------------- ChannelwiseLayerNorm, ONE-PASS (x cached in registers) ----------------
__global__ __launch_bounds__(256) void ln_kernel(
    const float* __restrict__ x, const float* __restrict__ gamma,
    const float* __restrict__ beta, __bf16* __restrict__ u)
{
  int tile = blockIdx.x & 127;
  int b    = blockIdx.x >> 7;
  int tsl = threadIdx.x & 7;
  int cg  = threadIdx.x >> 3;
  const float4* xp = (const float4*)(x + (size_t)b*CC*TT + tile*32) + tsl;
  float4 cv[16];
  float4 s = {0,0,0,0}, s2 = {0,0,0,0};
  #pragma unroll
  for (int j = 0; j < 16; ++j){
    float4 v = xp[(size_t)(cg*16 + j)*(TT/4)];
    cv[j] = v;
    s.x += v.x; s.y += v.y; s.z += v.z; s.w += v.w;
    s2.x = fmaf(v.x,v.x,s2.x); s2.y = fmaf(v.y,v.y,s2.y);
    s2.z = fmaf(v.z,v.z,s2.z); s2.w = fmaf(v.w,v.w,s2.w);
  }
  __shared__ float4 ls[32][8], ls2[32][8], mean_s[8], inv_s[8];
  ls[cg][tsl] = s; ls2[cg][tsl] = s2;
  __syncthreads();
  if (threadIdx.x < 8){
    float4 ss = {0,0,0,0}, ss2 = {0,0,0,0};
    #pragma unroll
    for (int g2 = 0; g2 < 32; ++g2){
      float4 a = ls[g2][threadIdx.x], b2 = ls2[g2][threadIdx.x];
      ss.x+=a.x; ss.y+=a.y; ss.z+=a.z; ss.w+=a.w;
      ss2.x+=b2.x; ss2.y+=b2.y; ss2.z+=b2.z; ss2.w+=b2.w;
    }
    float4 mn, iv;
    mn.x = ss.x*(1.f/CC); mn.y = ss.y*(1.f/CC); mn.z = ss.z*(1.f/CC); mn.w = ss.w*(1.f/CC);
    iv.x = rsqrtf(ss2.x*(1.f/CC) - mn.x*mn.x + 1e-5f);
    iv.y = rsqrtf(ss2.y*(1.f/CC) - mn.y*mn.y + 1e-5f);
    iv.z = rsqrtf(ss2.z*(1.f/CC) - mn.z*mn.z + 1e-5f);
    iv.w = rsqrtf(ss2.w*(1.f/CC) - mn.w*mn.w + 1e-5f);
    mean_s[threadIdx.x] = mn; inv_s[threadIdx.x] = iv;
  }
  __syncthreads();
  float4 mn = mean_s[tsl], iv = inv_s[tsl];
  __bf16* up = u + (size_t)b*CC*TT + tile*32 + tsl*4;
  #pragma unroll
  for (int j = 0; j < 16; ++j){
    int c = cg*16 + j;
    float4 v = cv[j];
    float gi = gamma[c], be = beta[c];
    bf4v o;
    o[0] = (__bf16)fmaf(gi*iv.x, v.x - mn.x, be);
    o[1] = (__bf16)fmaf(gi*iv.y, v.y - mn.y, be);
    o[2] = (__bf16)fmaf(gi*iv.z, v.z - mn.z, be);
    o[3] = (__bf16)fmaf(gi*iv.w, v.w - mn.w, be);
    *(bf4v*)&up[(size_t)c*TT] = o;
  }
}

// ---------------- build per-channel S4D basis matrices (bf16) ----------------
__global__ __launch_bounds__(256) void build_mats(
    const float* __restrict__ log_dt, const float* __restrict__ C_re,
    const float* __restrict__ C_im, const float* __restrict__ log_A_real,
    const float* __restrict__ A_imag, const float* __restrict__ Dp,
    __bf16* __restrict__ Tt, __bf16* __restrict__ V, __bf16* __restrict__ B2)
{
  __shared__ float cpart[4][64][33];
  __shared__ float kk[4][65];
  const int wv = threadIdx.x >> 6, lane = threadIdx.x & 63;
  const int c = blockIdx.x*4 + wv;
  const int m = lane & 31;
  float dt = expf(log_dt[c]);
  float Ar = -expf(log_A_real[c*NN2+m]);
  float Ai = A_imag[c*NN2+m];
  float er = expf(Ar*dt);
  float sw_, cw_; sincosf(Ai*dt, &sw_, &cw_);
  float wre = er*cw_, wim = er*sw_;
  float nr = wre-1.f, ni = wim;
  float inv = 1.f/(Ar*Ar + Ai*Ai);
  float qr = (nr*Ar + ni*Ai)*inv;
  float qi = (ni*Ar - nr*Ai)*inv;
  float Cr = C_re[c*NN2+m], Ci = C_im[c*NN2+m];
  float okr =  2.f*(Cr*qr - Ci*qi);
  float oki = -2.f*(Cr*qi + Ci*qr);
  __bf16* Ttc = Tt + (size_t)c*4096;
  __bf16* Vc  = V  + (size_t)c*4096;
  __bf16* B2c = B2 + (size_t)c*4096;
  if (lane < 32){
    float pre = 1.f, pim = 0.f;
    for (int l = 0; l <= 64; ++l){
      if (l <= 63){
        Vc[(2*m)*64   + (63-l)] = (__bf16)pre;
        Vc[(2*m+1)*64 + (63-l)] = (__bf16)pim;
      }
      float cR = fmaf(okr, pre,  oki*pim);
      float cQ = fmaf(oki, pre, -okr*pim);
      if (l <= 63) cpart[wv][l][m] = cR;
      if (l >= 1){
        B2c[(l-1)*64 + 2*m]   = (__bf16)cR;
        B2c[(l-1)*64 + 2*m+1] = (__bf16)cQ;
      }
      float npre = wre*pre - wim*pim;
      float npim = wre*pim + wim*pre;
      pre = npre; pim = npim;
    }
  }
  __syncthreads();
  float s = 0.f;
  #pragma unroll
  for (int mm = 0; mm < 32; ++mm) s += cpart[wv][lane][mm];
  if (lane == 0) s += Dp[c];
  kk[wv][lane] = s;
  __syncthreads();
  const int n = lane;
  #pragma unroll
  for (int kb = 0; kb < 8; ++kb){
    u16x8 v;
    #pragma unroll
    for (int e = 0; e < 8; ++e){
      int k = kb*8 + e;
      v[e] = bfbits((n >= k) ? kk[wv][n-k] : 0.f);
    }
    *(u16x8*)&Ttc[n*64 + kb*8] = v;
  }
}

// ---------------- fused S4D via MFMA: G=U@V -> scan -> Y=U@Tt+S0@B2 -> gelu ----------------
__global__ __launch_bounds__(128) void s4dm_kernel(
    const __bf16* __restrict__ u, const float* __restrict__ log_dt,
    const float* __restrict__ log_A_real, const float* __restrict__ A_imag,
    const __bf16* __restrict__ Tt, const __bf16* __restrict__ V,
    const __bf16* __restrict__ B2, __bf16* __restrict__ gout)
{
  __shared__ __align__(16) float gbuf[2][64][66];
  __shared__ __align__(16) unsigned short s0buf[2][64][72];
  const int wv = threadIdx.x >> 6, l = threadIdx.x & 63;
  const int lr = l & 15, q = l >> 4;
  const int seq = blockIdx.x*2 + wv;
  const int c = seq & (CC-1);
  const __bf16* Up  = u  + (size_t)seq*TT;
  const __bf16* Ttc = Tt + (size_t)c*4096;
  const __bf16* Vc  = V  + (size_t)c*4096;
  const __bf16* B2c = B2 + (size_t)c*4096;

  f4v acc[4][4];
  #pragma unroll
  for (int a=0;a<4;++a)
    #pragma unroll
    for (int b=0;b<4;++b)
      #pragma unroll
      for (int r=0;r<4;++r) acc[a][b][r] = 0.f;

  #pragma unroll
  for (int kw = 0; kw < 2; ++kw){
    bf8v af[4], bv[4];
    #pragma unroll
    for (int mt=0;mt<4;++mt)
      af[mt] = *(const bf8v*)(Up + (mt*16+lr)*64 + kw*32 + q*8);
    #pragma unroll
    for (int nt=0;nt<4;++nt)
      bv[nt] = *(const bf8v*)(Vc + (nt*16+lr)*64 + kw*32 + q*8);
    #pragma unroll
    for (int mt=0;mt<4;++mt)
      #pragma unroll
      for (int nt=0;nt<4;++nt)
        acc[mt][nt] = __builtin_amdgcn_mfma_f32_16x16x32_bf16(af[mt], bv[nt], acc[mt][nt], 0,0,0);
  }
  #pragma unroll
  for (int mt=0;mt<4;++mt)
    #pragma unroll
    for (int nt=0;nt<4;++nt)
      #pragma unroll
      for (int r=0;r<4;++r)
        gbuf[wv][mt*16 + q*4 + r][nt*16 + lr] = acc[mt][nt][r];
  __syncthreads();

  if (l < 32){
    const int m = l;
    float dt = expf(log_dt[c]);
    float Ar = -expf(log_A_real[c*NN2+m]);
    float Ai = A_imag[c*NN2+m];
    float er = expf(Ar*dt);
    float sw_, cw_; sincosf(Ai*dt, &sw_, &cw_);
    float wr_ = er*cw_, wi_ = er*sw_;
    #pragma unroll
    for (int sq2=0;sq2<6;++sq2){
      float a=wr_, b=wi_;
      wr_ = a*a - b*b; wi_ = 2.f*a*b;
    }
    float S0r=0.f, S0i=0.f;
    for (int j=0;j<64;++j){
      float gr = gbuf[wv][j][2*m], gi = gbuf[wv][j][2*m+1];
      s0buf[wv][j][2*m]   = bfbits(S0r);
      s0buf[wv][j][2*m+1] = bfbits(S0i);
      float nRe = fmaf(wr_, S0r, fmaf(-wi_, S0i, gr));
      float nIm = fmaf(wr_, S0i, fmaf( wi_, S0r, gi));
      S0r = nRe; S0i = nIm;
    }
  }
  __syncthreads();

  #pragma unroll
  for (int a=0;a<4;++a)
    #pragma unroll
    for (int b=0;b<4;++b)
      #pragma unroll
      for (int r=0;r<4;++r) acc[a][b][r] = 0.f;
  #pragma unroll
  for (int kw = 0; kw < 2; ++kw){
    bf8v af[4], bv[4];
    #pragma unroll
    for (int mt=0;mt<4;++mt)
      af[mt] = *(const bf8v*)(Up + (mt*16+lr)*64 + kw*32 + q*8);
    #pragma unroll
    for (int nt=0;nt<4;++nt)
      bv[nt] = *(const bf8v*)(Ttc + (nt*16+lr)*64 + kw*32 + q*8);
    #pragma unroll
    for (int mt=0;mt<4;++mt)
      #pragma unroll
      for (int nt=0;nt<4;++nt)
        acc[mt][nt] = __builtin_amdgcn_mfma_f32_16x16x32_bf16(af[mt], bv[nt], acc[mt][nt], 0,0,0);
  }
  #pragma unroll
  for (int kw = 0; kw < 2; ++kw){
    bf8v af[4], bv[4];
    #pragma unroll
    for (int mt=0;mt<4;++mt)
      af[mt] = *(const bf8v*)&s0buf[wv][mt*16+lr][kw*32 + q*8];
    #pragma unroll
    for (int nt=0;nt<4;++nt)
      bv[nt] = *(const bf8v*)(B2c + (nt*16+lr)*64 + kw*32 + q*8);
    #pragma unroll
    for (int mt=0;mt<4;++mt)
      #pragma unroll
      for (int nt=0;nt<4;++nt)
        acc[mt][nt] = __builtin_amdgcn_mfma_f32_16x16x32_bf16(af[mt], bv[nt], acc[mt][nt], 0,0,0);
  }
  __syncthreads();

  unsigned short (*ybuf)[72] = (unsigned short(*)[72])&gbuf[wv][0][0];
  #pragma unroll
  for (int mt=0;mt<4;++mt)
    #pragma unroll
    for (int nt=0;nt<4;++nt)
      #pragma unroll
      for (int r=0;r<4;++r)
        ybuf[mt*16 + q*4 + r][nt*16 + lr] = bfbits(fast_gelu(acc[mt][nt][r]));
  __syncthreads();
  u16x8* dst = (u16x8*)(gout + (size_t)seq*TT);
  for (int i = l; i < 512; i += 64){
    int row = i >> 3, cq = i & 7;
    dst[i] = *(const u16x8*)&ybuf[row][cq*8];
  }
}

// ---------------- transpose [B][C][T] bf16 -> [B][T][C] bf16 ----------------
__global__ __launch_bounds__(256) void tr_kernel(const __bf16* __restrict__ gin,
                                                 __bf16* __restrict__ gout)
{
  __shared__ __align__(16) unsigned short ts[64][72];
  int bt = blockIdx.x;
  int bc = blockIdx.y;
  int b  = blockIdx.z;
  int tid = threadIdx.x;
  const __bf16* gp = gin + ((size_t)b*CC + bc*64)*TT + (size_t)bt*64;
  for (int i = tid; i < 512; i += 256){
    int c = i >> 3, tq = i & 7;
    u16x8 v = *(const u16x8*)(gp + (size_t)c*TT + tq*8);
    #pragma unroll
    for (int s = 0; s < 8; ++s) ts[tq*8+s][c] = v[s];
  }
  __syncthreads();
  __bf16* op = gout + ((size_t)b*TT + bt*64)*CC + bc*64;
  for (int i = tid; i < 512; i += 256){
    int t = i >> 3, cq = i & 7;
    u16x8 v = *(const u16x8*)&ts[t][cq*8];
    *(u16x8*)(op + (size_t)t*CC + cq*8) = v;
  }
}

// ---------------- fp32 -> bf16 weight convert (all three weights, one dispatch) ----------------
__global__ __launch_bounds__(256) void cvt_all_kernel(
    const float4* __restrict__ w0, bf4v* __restrict__ o0, int n0,
    const float4* __restrict__ w1, bf4v* __restrict__ o1, int n1,
    const float4* __restrict__ w2, bf4v* __restrict__ o2, int n2)
{
  int total = n0 + n1 + n2;
  for (int i = blockIdx.x*256 + threadIdx.x; i < total; i += gridDim.x*256){
    const float4* src; bf4v* dst; int j = i;
    if (j < n0){ src = w0; dst = o0; }
    else if (j < n0 + n1){ j -= n0; src = w1; dst = o1; }
    else { j -= n0 + n1; src = w2; dst = o2; }
    float4 v = src[j];
    bf4v o; o[0]=(__bf16)v.x; o[1]=(__bf16)v.y; o[2]=(__bf16)v.z; o[3]=(__bf16)v.w;
    dst[j] = o;
  }
}

// ---------------- bf16 MFMA GEMM — round-12 structure (serial single-buffer,
// BK=64, 128x128 tile, 256 thr, XOR swizzle, hoisted offsets, XCD decode).
// MODE 0: GLU   — A=Wo[1024][512] dual, B=g_tm, out glu bf16 [tok][C]
// MODE 1: PReLU — A=W1[2048][512],      B=glu,  out h bf16 [tok][H]
// MODE 2: resid — A=W2[512][2048],      B=h,    out fp32 [b][ch][t] (+b2 +x)
template<int MODE>
__global__ __launch_bounds__(256) void mm_kernel(
    const __bf16* __restrict__ Aw, const __bf16* __restrict__ Bt,
    const float* __restrict__ bias, const float* __restrict__ aux,
    void* __restrict__ outp)
{
  constexpr int K  = (MODE==2) ? 2048 : 512;
  constexpr int NT = K/64;
  constexpr int LOGGM = (MODE==1) ? 4 : 2;
  constexpr int GM = 1 << LOGGM;

  __shared__ __align__(16) __bf16 As[128*64];
  __shared__ __align__(16) __bf16 Bs[128*64];
  __shared__ __align__(16) __bf16 As2[(MODE==0)?128*64:8];

  const int bid = blockIdx.x;
  const int X = bid & 7, L = bid >> 3;
  const int m0 = (L & (GM-1)) * 128;
  const int n0 = (X*16 + (L >> LOGGM)) * 128;

  const int tid = threadIdx.x;
  const int l = tid & 63;
  const int lr = l & 15, kh = l >> 4;
  const int w = tid >> 6;
  const int wr = w >> 1, wc = w & 1;
  const int swk = lr & 7;

  f4v acc[4][4];
  f4v acc2[(MODE==0)?4:1][(MODE==0)?4:1];
  #pragma unroll
  for (int a=0;a<4;++a)
    #pragma unroll
    for (int b=0;b<4;++b)
      #pragma unroll
      for (int r=0;r<4;++r) acc[a][b][r] = 0.f;
  if constexpr (MODE==0){
    #pragma unroll
    for (int a=0;a<4;++a)
      #pragma unroll
      for (int b=0;b<4;++b)
        #pragma unroll
        for (int r=0;r<4;++r) acc2[a][b][r] = 0.f;
  }

  const char* pA  = (const char*)Aw;
  const char* pA2 = (const char*)(Aw + (size_t)CC*K);
  const char* pB  = (const char*)Bt;

  int offA[4], offB[4];
  #pragma unroll
  for (int i = 0; i < 4; ++i){
    int cch = i*256 + tid;
    int row = cch >> 3;
    int pos = cch & 7;
    int qq  = pos ^ (row & 7);
    offA[i] = ((m0 + row)*K + qq*8)*2;
    offB[i] = ((n0 + row)*K + qq*8)*2;
  }

  #pragma unroll 1
  for (int kt = 0; kt < NT; ++kt){
    #pragma unroll
    for (int i = 0; i < 4; ++i){
      int cch = i*256 + tid;
      gload16(pA + (size_t)offA[i] + kt*128, (char*)As + cch*16);
      gload16(pB + (size_t)offB[i] + kt*128, (char*)Bs + cch*16);
      if constexpr (MODE==0)
        gload16(pA2 + (size_t)offA[i] + kt*128, (char*)As2 + cch*16);
    }
    __syncthreads();

    #pragma unroll
    for (int kk2 = 0; kk2 < 2; ++kk2){
      const int coff = ((kk2*4 + kh) ^ swk) * 16;
      bf8v af[4], bv4[4];
      #pragma unroll
      for (int mi=0;mi<4;++mi){
        int row = wr*64 + mi*16 + lr;
        af[mi] = *(const bf8v*)((const char*)As + row*128 + coff);
      }
      #pragma unroll
      for (int ni=0;ni<4;++ni){
        int row = wc*64 + ni*16 + lr;
        bv4[ni] = *(const bf8v*)((const char*)Bs + row*128 + coff);
      }
      if constexpr (MODE==0){
        bf8v af2[4];
        #pragma unroll
        for (int mi=0;mi<4;++mi){
          int row = wr*64 + mi*16 + lr;
          af2[mi] = *(const bf8v*)((const char*)As2 + row*128 + coff);
        }
        #pragma unroll
        for (int mi=0;mi<4;++mi)
          #pragma unroll
          for (int ni=0;ni<4;++ni){
            acc [mi][ni] = __builtin_amdgcn_mfma_f32_16x16x32_bf16(af [mi], bv4[ni], acc [mi][ni], 0,0,0);
            acc2[mi][ni] = __builtin_amdgcn_mfma_f32_16x16x32_bf16(af2[mi], bv4[ni], acc2[mi][ni], 0,0,0);
          }
      } else {
        #pragma unroll
        for (int mi=0;mi<4;++mi)
          #pragma unroll
          for (int ni=0;ni<4;++ni)
            acc[mi][ni] = __builtin_amdgcn_mfma_f32_16x16x32_bf16(af[mi], bv4[ni], acc[mi][ni], 0,0,0);
      }
    }
    __syncthreads();
  }

  // ---- epilogues ----
  if constexpr (MODE==0 || MODE==1){
    const int COUT = (MODE==0) ? CC : HH;
    __bf16* O = (__bf16*)outp;
    #pragma unroll
    for (int mi=0;mi<4;++mi){
      int m = m0 + wr*64 + mi*16 + kh*4;
      float4 bi = *(const float4*)&bias[m];
      float bia[4] = {bi.x, bi.y, bi.z, bi.w};
      float gta[4], paa[4];
      if constexpr (MODE==0){
        float4 bg = *(const float4*)&bias[CC + m];
        gta[0]=bg.x; gta[1]=bg.y; gta[2]=bg.z; gta[3]=bg.w;
      } else {
        float4 pa = *(const float4*)&aux[m];
        paa[0]=pa.x; paa[1]=pa.y; paa[2]=pa.z; paa[3]=pa.w;
      }
      #pragma unroll
      for (int ni=0;ni<4;++ni){
        int tok = n0 + wc*64 + ni*16 + lr;
        bf4v o;
        #pragma unroll
        for (int r=0;r<4;++r){
          float v = acc[mi][ni][r] + bia[r];
          if constexpr (MODE==0){
            float gate = acc2[mi][ni][r] + gta[r];
            v = v * fast_sigmoid(gate);
          } else {
            v = (v >= 0.f) ? v : paa[r]*v;
          }
          o[r] = (__bf16)v;
        }
        *(bf4v*)&O[(size_t)tok*COUT + m] = o;
      }
    }
  } else {
    float* O = (float*)outp;
    #pragma unroll
    for (int mi=0;mi<4;++mi){
      int chb = m0 + wr*64 + mi*16 + kh*4;
      float4 bi = *(const float4*)&bias[chb];
      float bia[4] = {bi.x, bi.y, bi.z, bi.w};
      #pragma unroll
      for (int ni=0;ni<4;++ni){
        int tok = n0 + wc*64 + ni*16 + lr;
        int b = tok >> 12, t = tok & 4095;
        size_t rb = ((size_t)(b*CC + chb))*TT + t;
        #pragma unroll
        for (int r=0;r<4;++r)
          O[rb + (size_t)r*TT] = acc[mi][ni][r] + bia[r] + aux[rb + (size_t)r*TT];
      }
    }
  }
}

// ---------------- host launch ----------------
extern "C" void kernel_launch(void* const* d_in, const int* in_sizes, int n_in,
                              void* d_out, int out_size, void* d_ws, size_t ws_size,
                              hipStream_t stream)
{
  const float* x          = (const float*)d_in[0];
  const float* gamma      = (const float*)d_in[1];
  const float* beta       = (const float*)d_in[2];
  const float* log_dt     = (const float*)d_in[3];
  const float* C_re       = (const float*)d_in[4];
  const float* C_im       = (const float*)d_in[5];
  const float* log_A_real = (const float*)d_in[6];
  const float* A_imag     = (const float*)d_in[7];
  const float* Dp         = (const float*)d_in[8];
  const float* Wo         = (const float*)d_in[9];
  const float* bo         = (const float*)d_in[10];
  const float* W1         = (const float*)d_in[11];
  const float* b1         = (const float*)d_in[12];
  const float* prelu_a    = (const float*)d_in[13];
  const float* W2         = (const float*)d_in[14];
  const float* b2         = (const float*)d_in[15];
  float* out = (float*)d_out;

  char* base = (char*)d_ws;
  const size_t SEGB = (size_t)BB*CC*TT*2;        // 16.78 MB bf16 plane
  __bf16* u_bf  = (__bf16*)(base);               // [B][C][T]
  __bf16* glu   = (__bf16*)(base);               // aliases u_bf (dead after s4dm)
  __bf16* g_cm  = (__bf16*)(base + SEGB);        // [B][C][T]
  __bf16* g_tm  = (__bf16*)(base + 2*SEGB);      // [B*T][C]
  __bf16* h     = (__bf16*)(base + SEGB);        // [16384][H] over dead g_cm/g_tm
  __bf16* Tt_all = (__bf16*)(base + 2*SEGB);     // basis alias g_tm (dead before tr)
  __bf16* V_all  = Tt_all + (size_t)CC*4096;
  __bf16* B2_all = V_all  + (size_t)CC*4096;
  __bf16* Wo_bf = (__bf16*)(base + 5*SEGB);      // weights: 5 MB
  __bf16* W1_bf = Wo_bf + (size_t)2*CC*CC;
  __bf16* W2_bf = W1_bf + (size_t)HH*CC;

  // one dispatch for all three weight converts (grid-stride)
  cvt_all_kernel<<<dim3(2048), 256, 0, stream>>>(
      (const float4*)Wo, (bf4v*)Wo_bf, 2*CC*CC/4,
      (const float4*)W1, (bf4v*)W1_bf, HH*CC/4,
      (const float4*)W2, (bf4v*)W2_bf, CC*HH/4);

  build_mats<<<dim3(CC/4), 256, 0, stream>>>(log_dt, C_re, C_im, log_A_real,
                                             A_imag, Dp, Tt_all, V_all, B2_all);
  ln_kernel<<<dim3(BB*(TT/32)), 256, 0, stream>>>(x, gamma, beta, u_bf);
  s4dm_kernel<<<dim3((BB*CC)/2), 128, 0, stream>>>(u_bf, log_dt, log_A_real, A_imag,
                                                   Tt_all, V_all, B2_all, g_cm);
  tr_kernel<<<dim3(TT/64, CC/64, BB), 256, 0, stream>>>(g_cm, g_tm);

  mm_kernel<0><<<dim3(4*128),  256, 0, stream>>>(Wo_bf, g_tm, bo, nullptr, (void*)glu);
  mm_kernel<1><<<dim3(16*128), 256, 0, stream>>>(W1_bf, glu, b1, prelu_a, (void*)h);
  mm_kernel<2><<<dim3(4*128),  256, 0, stream>>>(W2_bf, h, b2, x, (void*)out);
}

// Round 18
// 195.883 us; speedup vs baseline: 1.0896x; 1.0367x over previous
//
#include <hip/hip_runtime.h>
#include <math.h>

#define BB 4
#define CC 512
#define TT 4096
#define NN2 32
#define HH 2048

typedef __bf16 bf8v __attribute__((ext_vector_type(8)));
typedef __bf16 bf4v __attribute__((ext_vector_type(4)));
typedef float  f4v  __attribute__((ext_vector_type(4)));
typedef unsigned short u16x8 __attribute__((ext_vector_type(8)));

__device__ __forceinline__ void gload16(const void* g, void* l){
  __builtin_amdgcn_global_load_lds(
      (const __attribute__((address_space(1))) unsigned int*)g,
      (__attribute__((address_space(3))) unsigned int*)l, 16, 0, 0);
}
__device__ __forceinline__ float fast_gelu(float v){
  float x2 = v*v;
  float x  = 0.7978845608f*v*fmaf(0.044715f, x2, 1.0f);
  float t  = __expf(2.0f*x);
  return v - v*__builtin_amdgcn_rcpf(1.0f + t);
}
__device__ __forceinline__ float fast_sigmoid(float g){
  return __builtin_amdgcn_rcpf(1.0f + __expf(-g));
}
__device__ __forceinline__ unsigned short bfbits(float v){
  __bf16 h = (__bf16)v;
  return __builtin_bit_cast(unsigned short, h);
}

// ---------------- prep: build_mats + LayerNorm + weight-cvt in ONE dispatch ----------------
// blocks [0,128): per-channel S4D basis matrices (verbatim build_mats)
// blocks [128,640): one-pass channelwise LayerNorm (verbatim ln)
// blocks [640,1664): grid-stride fp32->bf16 convert of Wo|W1|W2
__global__ __launch_bounds__(256) void prep_kernel(
    // build_mats args
    const float* __restrict__ log_dt, const float* __restrict__ C_re,
    const float* __restrict__ C_im, const float* __restrict__ log_A_real,
    const float* __restrict__ A_imag, const float* __restrict__ Dp,
    __bf16* __restrict__ Tt, __bf16* __restrict__ V, __bf16* __restrict__ B2,
    // ln args
    const float* __restrict__ x, const float* __restrict__ gamma,
    const float* __restrict__ beta, __bf16* __restrict__ u,
    // cvt args
    const float4* __restrict__ w0, bf4v* __restrict__ o0, int n0,
    const float4* __restrict__ w1, bf4v* __restrict__ o1, int n1,
    const float4* __restrict__ w2, bf4v* __restrict__ o2, int n2)
{
  __shared__ float cpart[4][64][33];
  __shared__ float kk[4][65];
  __shared__ float4 ls[32][8], ls2[32][8], mean_s[8], inv_s[8];

  const int blk = blockIdx.x;
  if (blk < 128){
    // ---- build_mats (c-block = blk) ----
    const int wv = threadIdx.x >> 6, lane = threadIdx.x & 63;
    const int c = blk*4 + wv;
    const int m = lane & 31;
    float dt = expf(log_dt[c]);
    float Ar = -expf(log_A_real[c*NN2+m]);
    float Ai = A_imag[c*NN2+m];
    float er = expf(Ar*dt);
    float sw_, cw_; sincosf(Ai*dt, &sw_, &cw_);
    float wre = er*cw_, wim = er*sw_;
    float nr = wre-1.f, ni = wim;
    float inv = 1.f/(Ar*Ar + Ai*Ai);
    float qr = (nr*Ar + ni*Ai)*inv;
    float qi = (ni*Ar - nr*Ai)*inv;
    float Cr = C_re[c*NN2+m], Ci = C_im[c*NN2+m];
    float okr =  2.f*(Cr*qr - Ci*qi);
    float oki = -2.f*(Cr*qi + Ci*qr);
    __bf16* Ttc = Tt + (size_t)c*4096;
    __bf16* Vc  = V  + (size_t)c*4096;
    __bf16* B2c = B2 + (size_t)c*4096;
    if (lane < 32){
      float pre = 1.f, pim = 0.f;
      for (int l = 0; l <= 64; ++l){
        if (l <= 63){
          Vc[(2*m)*64   + (63-l)] = (__bf16)pre;
          Vc[(2*m+1)*64 + (63-l)] = (__bf16)pim;
        }
        float cR = fmaf(okr, pre,  oki*pim);
        float cQ = fmaf(oki, pre, -okr*pim);
        if (l <= 63) cpart[wv][l][m] = cR;
        if (l >= 1){
          B2c[(l-1)*64 + 2*m]   = (__bf16)cR;
          B2c[(l-1)*64 + 2*m+1] = (__bf16)cQ;
        }
        float npre = wre*pre - wim*pim;
        float npim = wre*pim + wim*pre;
        pre = npre; pim = npim;
      }
    }
    __syncthreads();
    float s = 0.f;
    #pragma unroll
    for (int mm = 0; mm < 32; ++mm) s += cpart[wv][lane][mm];
    if (lane == 0) s += Dp[c];
    kk[wv][lane] = s;
    __syncthreads();
    const int n = lane;
    #pragma unroll
    for (int kb = 0; kb < 8; ++kb){
      u16x8 v;
      #pragma unroll
      for (int e = 0; e < 8; ++e){
        int k = kb*8 + e;
        v[e] = bfbits((n >= k) ? kk[wv][n-k] : 0.f);
      }
      *(u16x8*)&Ttc[n*64 + kb*8] = v;
    }
  } else if (blk < 640){
    // ---- LayerNorm (tile-block = blk-128) ----
    int bid2 = blk - 128;
    int tile = bid2 & 127;
    int b    = bid2 >> 7;
    int tsl = threadIdx.x & 7;
    int cg  = threadIdx.x >> 3;
    const float4* xp = (const float4*)(x + (size_t)b*CC*TT + tile*32) + tsl;
    float4 cv[16];
    float4 s = {0,0,0,0}, s2 = {0,0,0,0};
    #pragma unroll
    for (int j = 0; j < 16; ++j){
      float4 v = xp[(size_t)(cg*16 + j)*(TT/4)];
      cv[j] = v;
      s.x += v.x; s.y += v.y; s.z += v.z; s.w += v.w;
      s2.x = fmaf(v.x,v.x,s2.x); s2.y = fmaf(v.y,v.y,s2.y);
      s2.z = fmaf(v.z,v.z,s2.z); s2.w = fmaf(v.w,v.w,s2.w);
    }
    ls[cg][tsl] = s; ls2[cg][tsl] = s2;
    __syncthreads();
    if (threadIdx.x < 8){
      float4 ss = {0,0,0,0}, ss2 = {0,0,0,0};
      #pragma unroll
      for (int g2 = 0; g2 < 32; ++g2){
        float4 a = ls[g2][threadIdx.x], b2 = ls2[g2][threadIdx.x];
        ss.x+=a.x; ss.y+=a.y; ss.z+=a.z; ss.w+=a.w;
        ss2.x+=b2.x; ss2.y+=b2.y; ss2.z+=b2.z; ss2.w+=b2.w;
      }
      float4 mn, iv;
      mn.x = ss.x*(1.f/CC); mn.y = ss.y*(1.f/CC); mn.z = ss.z*(1.f/CC); mn.w = ss.w*(1.f/CC);
      iv.x = rsqrtf(ss2.x*(1.f/CC) - mn.x*mn.x + 1e-5f);
      iv.y = rsqrtf(ss2.y*(1.f/CC) - mn.y*mn.y + 1e-5f);
      iv.z = rsqrtf(ss2.z*(1.f/CC) - mn.z*mn.z + 1e-5f);
      iv.w = rsqrtf(ss2.w*(1.f/CC) - mn.w*mn.w + 1e-5f);
      mean_s[threadIdx.x] = mn; inv_s[threadIdx.x] = iv;
    }
    __syncthreads();
    float4 mn = mean_s[tsl], iv = inv_s[tsl];
    __bf16* up = u + (size_t)b*CC*TT + tile*32 + tsl*4;
    #pragma unroll
    for (int j = 0; j < 16; ++j){
      int c = cg*16 + j;
      float4 v = cv[j];
      float gi = gamma[c], be = beta[c];
      bf4v o;
      o[0] = (__bf16)fmaf(gi*iv.x, v.x - mn.x, be);
      o[1] = (__bf16)fmaf(gi*iv.y, v.y - mn.y, be);
      o[2] = (__bf16)fmaf(gi*iv.z, v.z - mn.z, be);
      o[3] = (__bf16)fmaf(gi*iv.w, v.w - mn.w, be);
      *(bf4v*)&up[(size_t)c*TT] = o;
    }
  } else {
    // ---- weight converts (grid-stride over 1024 blocks) ----
    int total = n0 + n1 + n2;
    for (int i = (blk - 640)*256 + threadIdx.x; i < total; i += 1024*256){
      const float4* src; bf4v* dst; int j = i;
      if (j < n0){ src = w0; dst = o0; }
      else if (j < n0 + n1){ j -= n0; src = w1; dst = o1; }
      else { j -= n0 + n1; src = w2; dst = o2; }
      float4 v = src[j];
      bf4v o; o[0]=(__bf16)v.x; o[1]=(__bf16)v.y; o[2]=(__bf16)v.z; o[3]=(__bf16)v.w;
      dst[j] = o;
    }
  }
}

// ---------------- fused S4D via MFMA: G=U@V -> scan -> Y=U@Tt+S0@B2 -> gelu ----------------
__global__ __launch_bounds__(128) void s4dm_kernel(
    const __bf16* __restrict__ u, const float* __restrict__ log_dt,
    const float* __restrict__ log_A_real, const float* __restrict__ A_imag,
    const __bf16* __restrict__ Tt, const __bf16* __restrict__ V,
    const __bf16* __restrict__ B2, __bf16* __restrict__ gout)
{
  __shared__ __align__(16) float gbuf[2][64][66];
  __shared__ __align__(16) unsigned short s0buf[2][64][72];
  const int wv = threadIdx.x >> 6, l = threadIdx.x & 63;
  const int lr = l & 15, q = l >> 4;
  const int seq = blockIdx.x*2 + wv;
  const int c = seq & (CC-1);
  const __bf16* Up  = u  + (size_t)seq*TT;
  const __bf16* Ttc = Tt + (size_t)c*4096;
  const __bf16* Vc  = V  + (size_t)c*4096;
  const __bf16* B2c = B2 + (size_t)c*4096;

  f4v acc[4][4];
  #pragma unroll
  for (int a=0;a<4;++a)
    #pragma unroll
    for (int b=0;b<4;++b)
      #pragma unroll
      for (int r=0;r<4;++r) acc[a][b][r] = 0.f;

  #pragma unroll
  for (int kw = 0; kw < 2; ++kw){
    bf8v af[4], bv[4];
    #pragma unroll
    for (int mt=0;mt<4;++mt)
      af[mt] = *(const bf8v*)(Up + (mt*16+lr)*64 + kw*32 + q*8);
    #pragma unroll
    for (int nt=0;nt<4;++nt)
      bv[nt] = *(const bf8v*)(Vc + (nt*16+lr)*64 + kw*32 + q*8);
    #pragma unroll
    for (int mt=0;mt<4;++mt)
      #pragma unroll
      for (int nt=0;nt<4;++nt)
        acc[mt][nt] = __builtin_amdgcn_mfma_f32_16x16x32_bf16(af[mt], bv[nt], acc[mt][nt], 0,0,0);
  }
  #pragma unroll
  for (int mt=0;mt<4;++mt)
    #pragma unroll
    for (int nt=0;nt<4;++nt)
      #pragma unroll
      for (int r=0;r<4;++r)
        gbuf[wv][mt*16 + q*4 + r][nt*16 + lr] = acc[mt][nt][r];
  __syncthreads();

  if (l < 32){
    const int m = l;
    float dt = expf(log_dt[c]);
    float Ar = -expf(log_A_real[c*NN2+m]);
    float Ai = A_imag[c*NN2+m];
    float er = expf(Ar*dt);
    float sw_, cw_; sincosf(Ai*dt, &sw_, &cw_);
    float wr_ = er*cw_, wi_ = er*sw_;
    #pragma unroll
    for (int sq2=0;sq2<6;++sq2){
      float a=wr_, b=wi_;
      wr_ = a*a - b*b; wi_ = 2.f*a*b;
    }
    float S0r=0.f, S0i=0.f;
    for (int j=0;j<64;++j){
      float gr = gbuf[wv][j][2*m], gi = gbuf[wv][j][2*m+1];
      s0buf[wv][j][2*m]   = bfbits(S0r);
      s0buf[wv][j][2*m+1] = bfbits(S0i);
      float nRe = fmaf(wr_, S0r, fmaf(-wi_, S0i, gr));
      float nIm = fmaf(wr_, S0i, fmaf( wi_, S0r, gi));
      S0r = nRe; S0i = nIm;
    }
  }
  __syncthreads();

  #pragma unroll
  for (int a=0;a<4;++a)
    #pragma unroll
    for (int b=0;b<4;++b)
      #pragma unroll
      for (int r=0;r<4;++r) acc[a][b][r] = 0.f;
  #pragma unroll
  for (int kw = 0; kw < 2; ++kw){
    bf8v af[4], bv[4];
    #pragma unroll
    for (int mt=0;mt<4;++mt)
      af[mt] = *(const bf8v*)(Up + (mt*16+lr)*64 + kw*32 + q*8);
    #pragma unroll
    for (int nt=0;nt<4;++nt)
      bv[nt] = *(const bf8v*)(Ttc + (nt*16+lr)*64 + kw*32 + q*8);
    #pragma unroll
    for (int mt=0;mt<4;++mt)
      #pragma unroll
      for (int nt=0;nt<4;++nt)
        acc[mt][nt] = __builtin_amdgcn_mfma_f32_16x16x32_bf16(af[mt], bv[nt], acc[mt][nt], 0,0,0);
  }
  #pragma unroll
  for (int kw = 0; kw < 2; ++kw){
    bf8v af[4], bv[4];
    #pragma unroll
    for (int mt=0;mt<4;++mt)
      af[mt] = *(const bf8v*)&s0buf[wv][mt*16+lr][kw*32 + q*8];
    #pragma unroll
    for (int nt=0;nt<4;++nt)
      bv[nt] = *(const bf8v*)(B2c + (nt*16+lr)*64 + kw*32 + q*8);
    #pragma unroll
    for (int mt=0;mt<4;++mt)
      #pragma unroll
      for (int nt=0;nt<4;++nt)
        acc[mt][nt] = __builtin_amdgcn_mfma_f32_16x16x32_bf16(af[mt], bv[nt], acc[mt][nt], 0,0,0);
  }
  __syncthreads();

  unsigned short (*ybuf)[72] = (unsigned short(*)[72])&gbuf[wv][0][0];
  #pragma unroll
  for (int mt=0;mt<4;++mt)
    #pragma unroll
    for (int nt=0;nt<4;++nt)
      #pragma unroll
      for (int r=0;r<4;++r)
        ybuf[mt*16 + q*4 + r][nt*16 + lr] = bfbits(fast_gelu(acc[mt][nt][r]));
  __syncthreads();
  u16x8* dst = (u16x8*)(gout + (size_t)seq*TT);
  for (int i = l; i < 512; i += 64){
    int row = i >> 3, cq = i & 7;
    dst[i] = *(const u16x8*)&ybuf[row][cq*8];
  }
}

// ---------------- transpose [B][C][T] bf16 -> [B][T][C] bf16 ----------------
__global__ __launch_bounds__(256) void tr_kernel(const __bf16* __restrict__ gin,
                                                 __bf16* __restrict__ gout)
{
  __shared__ __align__(16) unsigned short ts[64][72];
  int bt = blockIdx.x;
  int bc = blockIdx.y;
  int b  = blockIdx.z;
  int tid = threadIdx.x;
  const __bf16* gp = gin + ((size_t)b*CC + bc*64)*TT + (size_t)bt*64;
  for (int i = tid; i < 512; i += 256){
    int c = i >> 3, tq = i & 7;
    u16x8 v = *(const u16x8*)(gp + (size_t)c*TT + tq*8);
    #pragma unroll
    for (int s = 0; s < 8; ++s) ts[tq*8+s][c] = v[s];
  }
  __syncthreads();
  __bf16* op = gout + ((size_t)b*TT + bt*64)*CC + bc*64;
  for (int i = tid; i < 512; i += 256){
    int t = i >> 3, cq = i & 7;
    u16x8 v = *(const u16x8*)&ts[t][cq*8];
    *(u16x8*)(op + (size_t)t*CC + cq*8) = v;
  }
}

// ---------------- bf16 MFMA GEMM — round-17 best (serial single-buffer,
// BK=64, 128x128 tile, 256 thr, XOR swizzle, hoisted offsets, XCD decode).
// MODE 0: GLU   — A=Wo[1024][512] dual, B=g_tm, out glu bf16 [tok][C]
// MODE 1: PReLU — A=W1[2048][512],      B=glu,  out h bf16 [tok][H]
// MODE 2: resid — A=W2[512][2048],      B=h,    out fp32 [b][ch][t] (+b2 +x)
template<int MODE>
__global__ __launch_bounds__(256) void mm_kernel(
    const __bf16* __restrict__ Aw, const __bf16* __restrict__ Bt,
    const float* __restrict__ bias, const float* __restrict__ aux,
    void* __restrict__ outp)
{
  constexpr int K  = (MODE==2) ? 2048 : 512;
  constexpr int NT = K/64;
  constexpr int LOGGM = (MODE==1) ? 4 : 2;
  constexpr int GM = 1 << LOGGM;

  __shared__ __align__(16) __bf16 As[128*64];
  __shared__ __align__(16) __bf16 Bs[128*64];
  __shared__ __align__(16) __bf16 As2[(MODE==0)?128*64:8];

  const int bid = blockIdx.x;
  const int X = bid & 7, L = bid >> 3;
  const int m0 = (L & (GM-1)) * 128;
  const int n0 = (X*16 + (L >> LOGGM)) * 128;

  const int tid = threadIdx.x;
  const int l = tid & 63;
  const int lr = l & 15, kh = l >> 4;
  const int w = tid >> 6;
  const int wr = w >> 1, wc = w & 1;
  const int swk = lr & 7;

  f4v acc[4][4];
  f4v acc2[(MODE==0)?4:1][(MODE==0)?4:1];
  #pragma unroll
  for (int a=0;a<4;++a)
    #pragma unroll
    for (int b=0;b<4;++b)
      #pragma unroll
      for (int r=0;r<4;++r) acc[a][b][r] = 0.f;
  if constexpr (MODE==0){
    #pragma unroll
    for (int a=0;a<4;++a)
      #pragma unroll
      for (int b=0;b<4;++b)
        #pragma unroll
        for (int r=0;r<4;++r) acc2[a][b][r] = 0.f;
  }

  const char* pA  = (const char*)Aw;
  const char* pA2 = (const char*)(Aw + (size_t)CC*K);
  const char* pB  = (const char*)Bt;

  int offA[4], offB[4];
  #pragma unroll
  for (int i = 0; i < 4; ++i){
    int cch = i*256 + tid;
    int row = cch >> 3;
    int pos = cch & 7;
    int qq  = pos ^ (row & 7);
    offA[i] = ((m0 + row)*K + qq*8)*2;
    offB[i] = ((n0 + row)*K + qq*8)*2;
  }

  #pragma unroll 1
  for (int kt = 0; kt < NT; ++kt){
    #pragma unroll
    for (int i = 0; i < 4; ++i){
      int cch = i*256 + tid;
      gload16(pA + (size_t)offA[i] + kt*128, (char*)As + cch*16);
      gload16(pB + (size_t)offB[i] + kt*128, (char*)Bs + cch*16);
      if constexpr (MODE==0)
        gload16(pA2 + (size_t)offA[i] + kt*128, (char*)As2 + cch*16);
    }
    __syncthreads();

    #pragma unroll
    for (int kk2 = 0; kk2 < 2; ++kk2){
      const int coff = ((kk2*4 + kh) ^ swk) * 16;
      bf8v af[4], bv4[4];
      #pragma unroll
      for (int mi=0;mi<4;++mi){
        int row = wr*64 + mi*16 + lr;
        af[mi] = *(const bf8v*)((const char*)As + row*128 + coff);
      }
      #pragma unroll
      for (int ni=0;ni<4;++ni){
        int row = wc*64 + ni*16 + lr;
        bv4[ni] = *(const bf8v*)((const char*)Bs + row*128 + coff);
      }
      if constexpr (MODE==0){
        bf8v af2[4];
        #pragma unroll
        for (int mi=0;mi<4;++mi){
          int row = wr*64 + mi*16 + lr;
          af2[mi] = *(const bf8v*)((const char*)As2 + row*128 + coff);
        }
        #pragma unroll
        for (int mi=0;mi<4;++mi)
          #pragma unroll
          for (int ni=0;ni<4;++ni){
            acc [mi][ni] = __builtin_amdgcn_mfma_f32_16x16x32_bf16(af [mi], bv4[ni], acc [mi][ni], 0,0,0);
            acc2[mi][ni] = __builtin_amdgcn_mfma_f32_16x16x32_bf16(af2[mi], bv4[ni], acc2[mi][ni], 0,0,0);
          }
      } else {
        #pragma unroll
        for (int mi=0;mi<4;++mi)
          #pragma unroll
          for (int ni=0;ni<4;++ni)
            acc[mi][ni] = __builtin_amdgcn_mfma_f32_16x16x32_bf16(af[mi], bv4[ni], acc[mi][ni], 0,0,0);
      }
    }
    __syncthreads();
  }

  // ---- epilogues ----
  if constexpr (MODE==0 || MODE==1){
    const int COUT = (MODE==0) ? CC : HH;
    __bf16* O = (__bf16*)outp;
    #pragma unroll
    for (int mi=0;mi<4;++mi){
      int m = m0 + wr*64 + mi*16 + kh*4;
      float4 bi = *(const float4*)&bias[m];
      float bia[4] = {bi.x, bi.y, bi.z, bi.w};
      float gta[4], paa[4];
      if constexpr (MODE==0){
        float4 bg = *(const float4*)&bias[CC + m];
        gta[0]=bg.x; gta[1]=bg.y; gta[2]=bg.z; gta[3]=bg.w;
      } else {
        float4 pa = *(const float4*)&aux[m];
        paa[0]=pa.x; paa[1]=pa.y; paa[2]=pa.z; paa[3]=pa.w;
      }
      #pragma unroll
      for (int ni=0;ni<4;++ni){
        int tok = n0 + wc*64 + ni*16 + lr;
        bf4v o;
        #pragma unroll
        for (int r=0;r<4;++r){
          float v = acc[mi][ni][r] + bia[r];
          if constexpr (MODE==0){
            float gate = acc2[mi][ni][r] + gta[r];
            v = v * fast_sigmoid(gate);
          } else {
            v = (v >= 0.f) ? v : paa[r]*v;
          }
          o[r] = (__bf16)v;
        }
        *(bf4v*)&O[(size_t)tok*COUT + m] = o;
      }
    }
  } else {
    float* O = (float*)outp;
    #pragma unroll
    for (int mi=0;mi<4;++mi){
      int chb = m0 + wr*64 + mi*16 + kh*4;
      float4 bi = *(const float4*)&bias[chb];
      float bia[4] = {bi.x, bi.y, bi.z, bi.w};
      #pragma unroll
      for (int ni=0;ni<4;++ni){
        int tok = n0 + wc*64 + ni*16 + lr;
        int b = tok >> 12, t = tok & 4095;
        size_t rb = ((size_t)(b*CC + chb))*TT + t;
        #pragma unroll
        for (int r=0;r<4;++r)
          O[rb + (size_t)r*TT] = acc[mi][ni][r] + bia[r] + aux[rb + (size_t)r*TT];
      }
    }
  }
}

// ---------------- host launch ----------------
extern "C" void kernel_launch(void* const* d_in, const int* in_sizes, int n_in,
                              void* d_out, int out_size, void* d_ws, size_t ws_size,
                              hipStream_t stream)
{
  const float* x          = (const float*)d_in[0];
  const float* gamma      = (const float*)d_in[1];
  const float* beta       = (const float*)d_in[2];
  const float* log_dt     = (const float*)d_in[3];
  const float* C_re       = (const float*)d_in[4];
  const float* C_im       = (const float*)d_in[5];
  const float* log_A_real = (const float*)d_in[6];
  const float* A_imag     = (const float*)d_in[7];
  const float* Dp         = (const float*)d_in[8];
  const float* Wo         = (const float*)d_in[9];
  const float* bo         = (const float*)d_in[10];
  const float* W1         = (const float*)d_in[11];
  const float* b1         = (const float*)d_in[12];
  const float* prelu_a    = (const float*)d_in[13];
  const float* W2         = (const float*)d_in[14];
  const float* b2         = (const float*)d_in[15];
  float* out = (float*)d_out;

  char* base = (char*)d_ws;
  const size_t SEGB = (size_t)BB*CC*TT*2;        // 16.78 MB bf16 plane
  __bf16* u_bf  = (__bf16*)(base);               // [B][C][T]
  __bf16* glu   = (__bf16*)(base);               // aliases u_bf (dead after s4dm)
  __bf16* g_cm  = (__bf16*)(base + SEGB);        // [B][C][T]
  __bf16* g_tm  = (__bf16*)(base + 2*SEGB);      // [B*T][C]
  __bf16* h     = (__bf16*)(base + SEGB);        // [16384][H] over dead g_cm/g_tm
  __bf16* Tt_all = (__bf16*)(base + 2*SEGB);     // basis alias g_tm (dead before tr)
  __bf16* V_all  = Tt_all + (size_t)CC*4096;
  __bf16* B2_all = V_all  + (size_t)CC*4096;
  __bf16* Wo_bf = (__bf16*)(base + 5*SEGB);      // weights: 5 MB
  __bf16* W1_bf = Wo_bf + (size_t)2*CC*CC;
  __bf16* W2_bf = W1_bf + (size_t)HH*CC;

  // fused prep: build_mats (128) + LayerNorm (512) + weight cvt (1024 grid-stride)
  prep_kernel<<<dim3(1664), 256, 0, stream>>>(
      log_dt, C_re, C_im, log_A_real, A_imag, Dp, Tt_all, V_all, B2_all,
      x, gamma, beta, u_bf,
      (const float4*)Wo, (bf4v*)Wo_bf, 2*CC*CC/4,
      (const float4*)W1, (bf4v*)W1_bf, HH*CC/4,
      (const float4*)W2, (bf4v*)W2_bf, CC*HH/4);

  s4dm_kernel<<<dim3((BB*CC)/2), 128, 0, stream>>>(u_bf, log_dt, log_A_real, A_imag,
                                                   Tt_all, V_all, B2_all, g_cm);
  tr_kernel<<<dim3(TT/64, CC/64, BB), 256, 0, stream>>>(g_cm, g_tm);

  mm_kernel<0><<<dim3(4*128),  256, 0, stream>>>(Wo_bf, g_tm, bo, nullptr, (void*)glu);
  mm_kernel<1><<<dim3(16*128), 256, 0, stream>>>(W1_bf, glu, b1, prelu_a, (void*)h);
  mm_kernel<2><<<dim3(4*128),  256, 0, stream>>>(W2_bf, h, b2, x, (void*)out);
}